// Round 19
// baseline (32.826 us; speedup 1.0000x reference)
//
#include <hip/hip_runtime.h>

#define HW 4096

typedef float f32x4 __attribute__((ext_vector_type(4)));
typedef __bf16 bf16x8 __attribute__((ext_vector_type(8)));

union F8 { bf16x8 v; unsigned long long q[2]; unsigned short u[8]; __bf16 h[8]; };

__device__ inline unsigned short f2bf(float f) {
    unsigned int u = __builtin_bit_cast(unsigned int, f);
    u += 0x7fffu + ((u >> 16) & 1u);   // RNE
    return (unsigned short)(u >> 16);
}
__device__ inline float bf2f(unsigned short h) {
    unsigned int u = ((unsigned int)h) << 16;
    return __builtin_bit_cast(float, u);
}
__device__ inline bf16x8 frag_lo(const unsigned short* p) {
    F8 f; f.q[0] = *(const unsigned long long*)p; f.q[1] = 0ull; return f.v;
}

#define MFMA16(a,b,c) __builtin_amdgcn_mfma_f32_16x16x32_bf16(a, b, c, 0, 0, 0)
#define EXP2(x) __builtin_amdgcn_exp2f(x)

// ---------------------------------------------------------------------------
// Kernel 1: projections, v2 = 1x x-traffic (was 4x).
// r13/r18 ledger: launch gap ~0, so T = P + A with P ~7-9us — dominated by
// 16MB of duplicated cold x reads (4 row-groups re-read each pixel column).
// v2: block = (b, 16-pixel tile); lane = pixel(4b) x c-quarter(2b); thread
// loads xv[16] (its quarter-column), per-row partial dot, combined via
// shfl_xor(16)+shfl_xor(32); 20 rows/wave x 4 waves = 80 rows. Same FMA
// count per thread (20x16=320) and same residency (grid 1024, (256,4) ->
// 16 waves/CU); x HBM traffic 16MB -> 4MB.
// Stores: lanes with quarter==(rr&3) store that row for their 16 pixels.
// vslot for 16-px blocks: bit4 of n = nt&1 (window u = nt>>1).
// ---------------------------------------------------------------------------
__global__ __launch_bounds__(256, 4) void proj_kernel(
    const float* __restrict__ x,
    const float* __restrict__ Wq, const float* __restrict__ bq,
    const float* __restrict__ Wk, const float* __restrict__ bk,
    const float* __restrict__ Wv, const float* __restrict__ bv,
    unsigned short* __restrict__ qpack, unsigned short* __restrict__ kpack,
    unsigned short* __restrict__ vt3)
{
    const float A2 = 0.51006977f;      // log2(e)/sqrt(8), folded into q
    __shared__ float ldsW[80][64];     // rows: 0..7 Wq*A2, 8..15 Wk, 16..79 Wv
    __shared__ float ldsB[80];

    const int blk  = blockIdx.x;
    const int b    = blk >> 8;         // 0..3
    const int nt   = blk & 255;        // 0..255 (16-pixel tiles)
    const int tid  = threadIdx.x;
    const int w    = tid >> 6;         // 0..3
    const int lane = tid & 63;
    const int px   = lane & 15;        // pixel in tile
    const int qu   = lane >> 4;        // c-quarter 0..3
    const int n    = nt * 16 + px;

    // stage W: 5120 floats = 1280 f32x4, 256 threads x 5 (as r17)
#pragma unroll
    for (int kk = 0; kk < 5; ++kk) {
        const int idx = tid + kk * 256;
        const int r   = idx >> 4;
        const int c   = (idx & 15) << 2;
        f32x4 val;
        if (r < 8) { val = *(const f32x4*)(Wq + r * 64 + c); val *= A2; }
        else if (r < 16) val = *(const f32x4*)(Wk + (r - 8) * 64 + c);
        else             val = *(const f32x4*)(Wv + (r - 16) * 64 + c);
        *(f32x4*)(&ldsW[r][c]) = val;
    }
    if (tid < 80) {
        ldsB[tid] = (tid < 8) ? bq[tid] * A2
                  : (tid < 16) ? bk[tid - 8] : bv[tid - 16];
    }
    __syncthreads();

    // this thread's c-quarter of pixel n's x column (16 values)
    const float* xb = x + ((size_t)b * 64 + qu * 16) * HW + n;
    float xv[16];
#pragma unroll
    for (int c = 0; c < 16; ++c) xv[c] = xb[(size_t)c * HW];

    auto rowdot = [&](int row) -> float {
        const float* wr = &ldsW[row][qu * 16];
        float a0 = 0.f, a1 = 0.f, a2 = 0.f, a3 = 0.f;
#pragma unroll
        for (int c4 = 0; c4 < 4; ++c4) {
            f32x4 wv = *(const f32x4*)(wr + c4 * 4);   // uniform broadcast
            a0 = fmaf(wv[0], xv[c4*4+0], a0);
            a1 = fmaf(wv[1], xv[c4*4+1], a1);
            a2 = fmaf(wv[2], xv[c4*4+2], a2);
            a3 = fmaf(wv[3], xv[c4*4+3], a3);
        }
        float p = (a0 + a1) + (a2 + a3);
        p += __shfl_xor(p, 16);            // combine quarters 0<->1, 2<->3
        p += __shfl_xor(p, 32);            // combine halves
        return p + ldsB[row];
    };

    // vt3 slot for pixel n (16-px block): bit4 of in-window index = nt&1
    const int vslot = (((px >> 2) & 3) << 3) + (px & 3) + ((nt & 1) << 2);
    unsigned short* vB = vt3 + ((size_t)(b * 128 + (nt >> 1)) * 64) * 32 + vslot;

    const int r0 = w * 20;
#pragma unroll
    for (int rr = 0; rr < 20; ++rr) {
        const int row = r0 + rr;           // wave-uniform
        float val = rowdot(row);
        if (qu == (rr & 3)) {              // 16 lanes store 16 pixels
            if (row < 8) {
                qpack[(size_t)(b * HW + n) * 8 + row] = f2bf(val);
            } else if (row < 16) {
                kpack[(size_t)(b * HW + n) * 8 + (row - 8)] = f2bf(val);
            } else {
                vB[(size_t)(row - 16) * 32] = f2bf(val);
            }
        }
    }
}

// ---------------------------------------------------------------------------
// Kernel 2: attention + skip — byte-identical to round 17's v12 (banked best:
// 4 i-chains, no duplicated softmax, ones-MFMA L, slab merge; A ~23us).
// ---------------------------------------------------------------------------
__global__ __launch_bounds__(512, 1) void attn_kernel(
    const unsigned short* __restrict__ qpack,
    const unsigned short* __restrict__ kpack,
    const unsigned short* __restrict__ vt3,
    const float* __restrict__ x,
    const float* __restrict__ gamma,
    float* __restrict__ out)
{
    const int blk  = blockIdx.x;
    const int slot = blk & 7;              // XCD slot = (b<<1)|(qt&1)
    const int j32  = blk >> 3;             // 0..31
    const int b    = slot >> 1;
    const int qt   = (j32 << 1) | (slot & 1);  // 0..63
    const int nb   = qt * 64;
    const int tid  = threadIdx.x;
    const int w    = tid >> 6;             // 0..7 = m-slice
    const int lane = tid & 63;
    const int g    = lane >> 4;
    const int ln   = lane & 15;

    __shared__ unsigned short ldsO[4][64][66];   // bf16 partial slabs
    __shared__ float ldsL[8][64];

    F8 zf; zf.q[0] = 0ull; zf.q[1] = 0ull;       // zero fragment (g>=1 pads)

    bf16x8 qf[4];
#pragma unroll
    for (int i = 0; i < 4; ++i)
        qf[i] = (g == 0)
              ? frag_lo(qpack + (size_t)(b * HW + nb + 16 * i + ln) * 8)
              : zf.v;

    F8 onesu;
#pragma unroll
    for (int e = 0; e < 8; ++e) onesu.u[e] = 0x3F80;   // bf16 1.0
    const bf16x8 ones = onesu.v;

    f32x4 o[4][4], ol[4];
#pragma unroll
    for (int i = 0; i < 4; ++i) {
#pragma unroll
        for (int j = 0; j < 4; ++j) o[i][j] = (f32x4){0,0,0,0};
        ol[i] = (f32x4){0,0,0,0};
    }

    const int mq = w * 512;                // this wave's m-slice
    const unsigned short* kb = kpack + (size_t)(b * HW + mq + ln) * 8;
    const unsigned short* vwin = vt3 + ((size_t)b * 128 + w * 16) * 2048
                               + ln * 32 + 8 * g;

#pragma unroll 2
    for (int ch = 0; ch < 16; ++ch) {
        const unsigned short* kp = kb + ch * 256;    // 32 K-rows x 8 ushorts
        bf16x8 kf0 = (g == 0) ? frag_lo(kp)       : zf.v;
        bf16x8 kf1 = (g == 0) ? frag_lo(kp + 128) : zf.v;
        const unsigned short* vp = vwin + (size_t)ch * 2048;
        bf16x8 vf0 = *(const bf16x8*)(vp);           // c rows ln
        bf16x8 vf1 = *(const bf16x8*)(vp + 512);     // c rows 16+ln
        bf16x8 vf2 = *(const bf16x8*)(vp + 1024);    // c rows 32+ln
        bf16x8 vf3 = *(const bf16x8*)(vp + 1536);    // c rows 48+ln

        const f32x4 z = {0.f, 0.f, 0.f, 0.f};
#pragma unroll
        for (int i = 0; i < 4; ++i) {
            f32x4 s0 = MFMA16(kf0, qf[i], z);
            f32x4 s1 = MFMA16(kf1, qf[i], z);
            F8 pa;
#pragma unroll
            for (int r = 0; r < 4; ++r) {
                pa.h[r]     = (__bf16)EXP2(s0[r]);
                pa.h[r + 4] = (__bf16)EXP2(s1[r]);
            }
            o[i][0] = MFMA16(pa.v, vf0, o[i][0]);
            o[i][1] = MFMA16(pa.v, vf1, o[i][1]);
            o[i][2] = MFMA16(pa.v, vf2, o[i][2]);
            o[i][3] = MFMA16(pa.v, vf3, o[i][3]);
            ol[i]   = MFMA16(pa.v, ones, ol[i]);
        }
    }

    // two-phase slab merge
    if (w < 4) {
#pragma unroll
        for (int i = 0; i < 4; ++i)
#pragma unroll
            for (int r = 0; r < 4; ++r)
#pragma unroll
                for (int j = 0; j < 4; ++j)
                    ldsO[w][16 * i + 4 * g + r][16 * j + ln] = f2bf(o[i][j][r]);
    }
    if (ln == 0) {
#pragma unroll
        for (int i = 0; i < 4; ++i)
#pragma unroll
            for (int r = 0; r < 4; ++r)
                ldsL[w][16 * i + 4 * g + r] = ol[i][r];
    }
    __syncthreads();
    if (w >= 4) {
        const int s = w - 4;
#pragma unroll
        for (int i = 0; i < 4; ++i)
#pragma unroll
            for (int r = 0; r < 4; ++r)
#pragma unroll
                for (int j = 0; j < 4; ++j) {
                    unsigned short* p = &ldsO[s][16 * i + 4 * g + r][16 * j + ln];
                    *p = f2bf(bf2f(*p) + o[i][j][r]);
                }
    }
    __syncthreads();

    const int q  = tid & 63;               // query row 0..63
    const int cg = tid >> 6;               // 0..7
    float L = 0.f;
#pragma unroll
    for (int wv = 0; wv < 8; ++wv) L += ldsL[wv][q];
    const float inv = 1.0f / L;
    const float gm  = gamma[0];
#pragma unroll
    for (int jj = 0; jj < 8; ++jj) {
        const int c = cg + 8 * jj;         // 0..63
        float Ov = bf2f(ldsO[0][q][c]) + bf2f(ldsO[1][q][c])
                 + bf2f(ldsO[2][q][c]) + bf2f(ldsO[3][q][c]);
        const size_t idx = (size_t)(b * 64 + c) * HW + nb + q;
        out[idx] = fmaf(gm, Ov * inv, x[idx]);
    }
}

extern "C" void kernel_launch(void* const* d_in, const int* in_sizes, int n_in,
                              void* d_out, int out_size, void* d_ws, size_t ws_size,
                              hipStream_t stream) {
    const float* x  = (const float*)d_in[0];
    const float* Wq = (const float*)d_in[1];
    const float* bq = (const float*)d_in[2];
    const float* Wk = (const float*)d_in[3];
    const float* bk = (const float*)d_in[4];
    const float* Wv = (const float*)d_in[5];
    const float* bv = (const float*)d_in[6];
    const float* gm = (const float*)d_in[7];

    // ws layout: qpack 256KB | kpack 256KB | vt3 2MB  (total 2.5MB)
    unsigned short* qpack = (unsigned short*)d_ws;
    unsigned short* kpack = qpack + 4 * HW * 8;
    unsigned short* vt3   = kpack + 4 * HW * 8;
    float* out = (float*)d_out;

    proj_kernel<<<1024, 256, 0, stream>>>(x, Wq, bq, Wk, bk, Wv, bv,
                                          qpack, kpack, vt3);
    attn_kernel<<<256, 512, 0, stream>>>(qpack, kpack, vt3, x, gm, out);
}

// Round 20
// 31.045 us; speedup vs baseline: 1.0574x; 1.0574x over previous
//
#include <hip/hip_runtime.h>

#define HW 4096

typedef float f32x4 __attribute__((ext_vector_type(4)));
typedef __bf16 bf16x8 __attribute__((ext_vector_type(8)));

union F8 { bf16x8 v; unsigned long long q[2]; unsigned short u[8]; __bf16 h[8]; };

__device__ inline unsigned short f2bf(float f) {
    unsigned int u = __builtin_bit_cast(unsigned int, f);
    u += 0x7fffu + ((u >> 16) & 1u);   // RNE
    return (unsigned short)(u >> 16);
}
__device__ inline float bf2f(unsigned short h) {
    unsigned int u = ((unsigned int)h) << 16;
    return __builtin_bit_cast(float, u);
}
__device__ inline bf16x8 frag_lo(const unsigned short* p) {
    F8 f; f.q[0] = *(const unsigned long long*)p; f.q[1] = 0ull; return f.v;
}

#define MFMA16(a,b,c) __builtin_amdgcn_mfma_f32_16x16x32_bf16(a, b, c, 0, 0, 0)
#define EXP2(x) __builtin_amdgcn_exp2f(x)

// ---------------------------------------------------------------------------
// Kernel 1: projections — r12-exact (banked best; r19's shuffle variant
// regressed: x is L2/L3-warm during replays, so the 2 shfl/row cost more
// than the saved traffic).
// ---------------------------------------------------------------------------
__global__ __launch_bounds__(256, 4) void proj_kernel(
    const float* __restrict__ x,
    const float* __restrict__ Wq, const float* __restrict__ bq,
    const float* __restrict__ Wk, const float* __restrict__ bk,
    const float* __restrict__ Wv, const float* __restrict__ bv,
    unsigned short* __restrict__ qpack, unsigned short* __restrict__ kpack,
    unsigned short* __restrict__ vt3)
{
    const float A2 = 0.51006977f;      // log2(e)/sqrt(8), folded into q
    __shared__ float ldsW[80][64];
    __shared__ float ldsB[80];

    const int blk   = blockIdx.x;
    const int b     = blk >> 8;
    const int rest  = blk & 255;
    const int ntile = rest >> 2;
    const int rg    = rest & 3;
    const int tid   = threadIdx.x;
    const int w     = tid >> 6;
    const int lane  = tid & 63;
    const int n     = ntile * 64 + lane;

#pragma unroll
    for (int kk = 0; kk < 5; ++kk) {
        const int idx = tid + kk * 256;
        const int r   = idx >> 4;
        const int c   = (idx & 15) << 2;
        f32x4 val;
        if (r < 8) { val = *(const f32x4*)(Wq + r * 64 + c); val *= A2; }
        else if (r < 16) val = *(const f32x4*)(Wk + (r - 8) * 64 + c);
        else             val = *(const f32x4*)(Wv + (r - 16) * 64 + c);
        *(f32x4*)(&ldsW[r][c]) = val;
    }
    if (tid < 80) {
        ldsB[tid] = (tid < 8) ? bq[tid] * A2
                  : (tid < 16) ? bk[tid - 8] : bv[tid - 16];
    }
    __syncthreads();

    const float* xb = x + (size_t)b * 64 * HW + n;
    float xv[64];
#pragma unroll
    for (int c = 0; c < 64; ++c) xv[c] = xb[c * HW];

    auto rowdot = [&](int row) -> float {
        const float* wr = &ldsW[row][0];
        float a0 = 0.f, a1 = 0.f, a2 = 0.f, a3 = 0.f;
#pragma unroll
        for (int c4 = 0; c4 < 16; ++c4) {
            f32x4 wv = *(const f32x4*)(wr + c4 * 4);
            a0 = fmaf(wv[0], xv[c4*4+0], a0);
            a1 = fmaf(wv[1], xv[c4*4+1], a1);
            a2 = fmaf(wv[2], xv[c4*4+2], a2);
            a3 = fmaf(wv[3], xv[c4*4+3], a3);
        }
        return (a0 + a1) + (a2 + a3) + ldsB[row];
    };

    const int vslot = (((n >> 2) & 3) << 3) + (n & 3) + (((n >> 4) & 1) << 2);
    unsigned short* vB = vt3 + ((size_t)(b * 128 + (n >> 5)) * 64) * 32 + vslot;

    const int r0 = rg * 20 + w * 5;
#pragma unroll
    for (int rr = 0; rr < 5; ++rr) {
        const int row = r0 + rr;
        float val = rowdot(row);
        if (row < 8) {
            qpack[(size_t)(b * HW + n) * 8 + row] = f2bf(val);
        } else if (row < 16) {
            kpack[(size_t)(b * HW + n) * 8 + (row - 8)] = f2bf(val);
        } else {
            vB[(size_t)(row - 16) * 32] = f2bf(val);
        }
    }
}

// ---------------------------------------------------------------------------
// Kernel 2: attention + skip, v13 = v12 with L moved off the MFMA pipe.
// Cycle model (corrected per-SIMD units: 1 MFMA 16x16x32 ~ 19.4 cyc/SIMD):
// v12 = 28 MFMA/chunk -> 7.3us matrix-pipe issue at 2 waves/SIMD; ones-MFMA
// was 4/chunk = ~1.0us of that, replaceable by 32 VALU adds/chunk (~64 cyc,
// VALU pipe has headroom: 4.3us). Cross-lane L reduce (shfl_xor 16,32)
// deferred to AFTER the chunk loop (psum is linear). Also -16 VGPR (ol gone).
// Everything else identical to v12 (banked best).
// ---------------------------------------------------------------------------
__global__ __launch_bounds__(512, 1) void attn_kernel(
    const unsigned short* __restrict__ qpack,
    const unsigned short* __restrict__ kpack,
    const unsigned short* __restrict__ vt3,
    const float* __restrict__ x,
    const float* __restrict__ gamma,
    float* __restrict__ out)
{
    const int blk  = blockIdx.x;
    const int slot = blk & 7;              // XCD slot = (b<<1)|(qt&1)
    const int j32  = blk >> 3;             // 0..31
    const int b    = slot >> 1;
    const int qt   = (j32 << 1) | (slot & 1);  // 0..63
    const int nb   = qt * 64;
    const int tid  = threadIdx.x;
    const int w    = tid >> 6;             // 0..7 = m-slice
    const int lane = tid & 63;
    const int g    = lane >> 4;
    const int ln   = lane & 15;

    __shared__ unsigned short ldsO[4][64][66];   // bf16 partial slabs
    __shared__ float ldsL[8][64];

    F8 zf; zf.q[0] = 0ull; zf.q[1] = 0ull;       // zero fragment (g>=1 pads)

    bf16x8 qf[4];
#pragma unroll
    for (int i = 0; i < 4; ++i)
        qf[i] = (g == 0)
              ? frag_lo(qpack + (size_t)(b * HW + nb + 16 * i + ln) * 8)
              : zf.v;

    f32x4 o[4][4];
    float psum[4];
#pragma unroll
    for (int i = 0; i < 4; ++i) {
#pragma unroll
        for (int j = 0; j < 4; ++j) o[i][j] = (f32x4){0,0,0,0};
        psum[i] = 0.f;
    }

    const int mq = w * 512;                // this wave's m-slice
    const unsigned short* kb = kpack + (size_t)(b * HW + mq + ln) * 8;
    const unsigned short* vwin = vt3 + ((size_t)b * 128 + w * 16) * 2048
                               + ln * 32 + 8 * g;

#pragma unroll 2
    for (int ch = 0; ch < 16; ++ch) {
        const unsigned short* kp = kb + ch * 256;    // 32 K-rows x 8 ushorts
        bf16x8 kf0 = (g == 0) ? frag_lo(kp)       : zf.v;
        bf16x8 kf1 = (g == 0) ? frag_lo(kp + 128) : zf.v;
        const unsigned short* vp = vwin + (size_t)ch * 2048;
        bf16x8 vf0 = *(const bf16x8*)(vp);           // c rows ln
        bf16x8 vf1 = *(const bf16x8*)(vp + 512);     // c rows 16+ln
        bf16x8 vf2 = *(const bf16x8*)(vp + 1024);    // c rows 32+ln
        bf16x8 vf3 = *(const bf16x8*)(vp + 1536);    // c rows 48+ln

        const f32x4 z = {0.f, 0.f, 0.f, 0.f};
#pragma unroll
        for (int i = 0; i < 4; ++i) {
            f32x4 s0 = MFMA16(kf0, qf[i], z);
            f32x4 s1 = MFMA16(kf1, qf[i], z);
            F8 pa;
            float sacc = 0.f;
#pragma unroll
            for (int r = 0; r < 4; ++r) {
                float e0 = EXP2(s0[r]);
                float e1 = EXP2(s1[r]);
                sacc += e0 + e1;
                pa.h[r]     = (__bf16)e0;
                pa.h[r + 4] = (__bf16)e1;
            }
            psum[i] += sacc;
            o[i][0] = MFMA16(pa.v, vf0, o[i][0]);
            o[i][1] = MFMA16(pa.v, vf1, o[i][1]);
            o[i][2] = MFMA16(pa.v, vf2, o[i][2]);
            o[i][3] = MFMA16(pa.v, vf3, o[i][3]);
        }
    }

    // deferred cross-lane L reduce: sum the 4 g-groups (lane bits 4,5)
#pragma unroll
    for (int i = 0; i < 4; ++i) {
        psum[i] += __shfl_xor(psum[i], 16);
        psum[i] += __shfl_xor(psum[i], 32);
    }

    // two-phase slab merge
    if (w < 4) {
#pragma unroll
        for (int i = 0; i < 4; ++i)
#pragma unroll
            for (int r = 0; r < 4; ++r)
#pragma unroll
                for (int j = 0; j < 4; ++j)
                    ldsO[w][16 * i + 4 * g + r][16 * j + ln] = f2bf(o[i][j][r]);
    }
    if (lane < 16) {                        // g==0 lanes hold full L
#pragma unroll
        for (int i = 0; i < 4; ++i)
            ldsL[w][16 * i + ln] = psum[i];
    }
    __syncthreads();
    if (w >= 4) {
        const int s = w - 4;
#pragma unroll
        for (int i = 0; i < 4; ++i)
#pragma unroll
            for (int r = 0; r < 4; ++r)
#pragma unroll
                for (int j = 0; j < 4; ++j) {
                    unsigned short* p = &ldsO[s][16 * i + 4 * g + r][16 * j + ln];
                    *p = f2bf(bf2f(*p) + o[i][j][r]);
                }
    }
    __syncthreads();

    const int q  = tid & 63;               // query row 0..63
    const int cg = tid >> 6;               // 0..7
    float L = 0.f;
#pragma unroll
    for (int wv = 0; wv < 8; ++wv) L += ldsL[wv][q];
    const float inv = 1.0f / L;
    const float gm  = gamma[0];
#pragma unroll
    for (int jj = 0; jj < 8; ++jj) {
        const int c = cg + 8 * jj;         // 0..63
        float Ov = bf2f(ldsO[0][q][c]) + bf2f(ldsO[1][q][c])
                 + bf2f(ldsO[2][q][c]) + bf2f(ldsO[3][q][c]);
        const size_t idx = (size_t)(b * 64 + c) * HW + nb + q;
        out[idx] = fmaf(gm, Ov * inv, x[idx]);
    }
}

extern "C" void kernel_launch(void* const* d_in, const int* in_sizes, int n_in,
                              void* d_out, int out_size, void* d_ws, size_t ws_size,
                              hipStream_t stream) {
    const float* x  = (const float*)d_in[0];
    const float* Wq = (const float*)d_in[1];
    const float* bq = (const float*)d_in[2];
    const float* Wk = (const float*)d_in[3];
    const float* bk = (const float*)d_in[4];
    const float* Wv = (const float*)d_in[5];
    const float* bv = (const float*)d_in[6];
    const float* gm = (const float*)d_in[7];

    // ws layout: qpack 256KB | kpack 256KB | vt3 2MB  (total 2.5MB)
    unsigned short* qpack = (unsigned short*)d_ws;
    unsigned short* kpack = qpack + 4 * HW * 8;
    unsigned short* vt3   = kpack + 4 * HW * 8;
    float* out = (float*)d_out;

    proj_kernel<<<1024, 256, 0, stream>>>(x, Wq, bq, Wk, bk, Wv, bv,
                                          qpack, kpack, vt3);
    attn_kernel<<<256, 512, 0, stream>>>(qpack, kpack, vt3, x, gm, out);
}

// Round 22
// 30.897 us; speedup vs baseline: 1.0624x; 1.0048x over previous
//
#include <hip/hip_runtime.h>

#define HW 4096

typedef float f32x4 __attribute__((ext_vector_type(4)));
typedef __bf16 bf16x8 __attribute__((ext_vector_type(8)));
typedef short s16x4 __attribute__((ext_vector_type(4)));

union F8 { bf16x8 v; unsigned long long q[2]; unsigned short u[8]; __bf16 h[8]; };

__device__ inline unsigned short f2bf(float f) {
    unsigned int u = __builtin_bit_cast(unsigned int, f);
    u += 0x7fffu + ((u >> 16) & 1u);   // RNE
    return (unsigned short)(u >> 16);
}
__device__ inline float bf2f(unsigned short h) {
    unsigned int u = ((unsigned int)h) << 16;
    return __builtin_bit_cast(float, u);
}
__device__ inline bf16x8 frag_lo(const unsigned short* p) {
    F8 f; f.q[0] = *(const unsigned long long*)p; f.q[1] = 0ull; return f.v;
}
__device__ inline s16x4 frag4s(const unsigned short* p) {
    union { s16x4 v; unsigned long long q; } f;
    f.q = *(const unsigned long long*)p; return f.v;
}

#define MFMA16(a,b,c) __builtin_amdgcn_mfma_f32_16x16x32_bf16(a, b, c, 0, 0, 0)
#define EXP2(x) __builtin_amdgcn_exp2f(x)

// K=16 S-MFMA via BUILTIN (compiler handles MFMA hazards/reg tuples — the
// r21 inline-asm version NaN'd). Compile-time fallback to the v13 K=32 path.
#if defined(__has_builtin)
#if __has_builtin(__builtin_amdgcn_mfma_f32_16x16x16bf16_1k)
#define HAVE_K16 1
__device__ inline f32x4 SMFMA16x16(s16x4 a, s16x4 b, f32x4 c) {
    return __builtin_amdgcn_mfma_f32_16x16x16bf16_1k(a, b, c, 0, 0, 0);
}
#endif
#endif

// ---------------------------------------------------------------------------
// Kernel 1: projections — r12-exact (banked best).
// ---------------------------------------------------------------------------
__global__ __launch_bounds__(256, 4) void proj_kernel(
    const float* __restrict__ x,
    const float* __restrict__ Wq, const float* __restrict__ bq,
    const float* __restrict__ Wk, const float* __restrict__ bk,
    const float* __restrict__ Wv, const float* __restrict__ bv,
    unsigned short* __restrict__ qpack, unsigned short* __restrict__ kpack,
    unsigned short* __restrict__ vt3)
{
    const float A2 = 0.51006977f;      // log2(e)/sqrt(8), folded into q
    __shared__ float ldsW[80][64];
    __shared__ float ldsB[80];

    const int blk   = blockIdx.x;
    const int b     = blk >> 8;
    const int rest  = blk & 255;
    const int ntile = rest >> 2;
    const int rg    = rest & 3;
    const int tid   = threadIdx.x;
    const int w     = tid >> 6;
    const int lane  = tid & 63;
    const int n     = ntile * 64 + lane;

#pragma unroll
    for (int kk = 0; kk < 5; ++kk) {
        const int idx = tid + kk * 256;
        const int r   = idx >> 4;
        const int c   = (idx & 15) << 2;
        f32x4 val;
        if (r < 8) { val = *(const f32x4*)(Wq + r * 64 + c); val *= A2; }
        else if (r < 16) val = *(const f32x4*)(Wk + (r - 8) * 64 + c);
        else             val = *(const f32x4*)(Wv + (r - 16) * 64 + c);
        *(f32x4*)(&ldsW[r][c]) = val;
    }
    if (tid < 80) {
        ldsB[tid] = (tid < 8) ? bq[tid] * A2
                  : (tid < 16) ? bk[tid - 8] : bv[tid - 16];
    }
    __syncthreads();

    const float* xb = x + (size_t)b * 64 * HW + n;
    float xv[64];
#pragma unroll
    for (int c = 0; c < 64; ++c) xv[c] = xb[c * HW];

    auto rowdot = [&](int row) -> float {
        const float* wr = &ldsW[row][0];
        float a0 = 0.f, a1 = 0.f, a2 = 0.f, a3 = 0.f;
#pragma unroll
        for (int c4 = 0; c4 < 16; ++c4) {
            f32x4 wv = *(const f32x4*)(wr + c4 * 4);
            a0 = fmaf(wv[0], xv[c4*4+0], a0);
            a1 = fmaf(wv[1], xv[c4*4+1], a1);
            a2 = fmaf(wv[2], xv[c4*4+2], a2);
            a3 = fmaf(wv[3], xv[c4*4+3], a3);
        }
        return (a0 + a1) + (a2 + a3) + ldsB[row];
    };

    const int vslot = (((n >> 2) & 3) << 3) + (n & 3) + (((n >> 4) & 1) << 2);
    unsigned short* vB = vt3 + ((size_t)(b * 128 + (n >> 5)) * 64) * 32 + vslot;

    const int r0 = rg * 20 + w * 5;
#pragma unroll
    for (int rr = 0; rr < 5; ++rr) {
        const int row = r0 + rr;
        float val = rowdot(row);
        if (row < 8) {
            qpack[(size_t)(b * HW + n) * 8 + row] = f2bf(val);
        } else if (row < 16) {
            kpack[(size_t)(b * HW + n) * 8 + (row - 8)] = f2bf(val);
        } else {
            vB[(size_t)(row - 16) * 32] = f2bf(val);
        }
    }
}

// ---------------------------------------------------------------------------
// Kernel 2: attention + skip, v15 = v13 with K=16 S-MFMA via builtin (if
// available; else exact v13 K=32 path). The slot->d assignment (group g
// holds d=4g..4g+3, g>=2 zero) is used for BOTH Q and K, so the dot over
// matched slots is exact regardless of the HW k permutation. Rest identical
// to v13 (banked 31.0us): VALU psum L, deferred shfl reduce, slab merge.
// ---------------------------------------------------------------------------
__global__ __launch_bounds__(512, 1) void attn_kernel(
    const unsigned short* __restrict__ qpack,
    const unsigned short* __restrict__ kpack,
    const unsigned short* __restrict__ vt3,
    const float* __restrict__ x,
    const float* __restrict__ gamma,
    float* __restrict__ out)
{
    const int blk  = blockIdx.x;
    const int slot = blk & 7;              // XCD slot = (b<<1)|(qt&1)
    const int j32  = blk >> 3;             // 0..31
    const int b    = slot >> 1;
    const int qt   = (j32 << 1) | (slot & 1);  // 0..63
    const int nb   = qt * 64;
    const int tid  = threadIdx.x;
    const int w    = tid >> 6;             // 0..7 = m-slice
    const int lane = tid & 63;
    const int g    = lane >> 4;
    const int ln   = lane & 15;

    __shared__ unsigned short ldsO[4][64][66];   // bf16 partial slabs
    __shared__ float ldsL[8][64];

#if HAVE_K16
    const s16x4 z4 = {0, 0, 0, 0};
    // Q frags (K=16): slot-group g holds d = 4g..4g+3; g>=2 zero
    s16x4 qf[4];
#pragma unroll
    for (int i = 0; i < 4; ++i)
        qf[i] = (g < 2)
              ? frag4s(qpack + (size_t)(b * HW + nb + 16 * i + ln) * 8 + 4 * g)
              : z4;
#else
    F8 zf; zf.q[0] = 0ull; zf.q[1] = 0ull;
    bf16x8 qf[4];
#pragma unroll
    for (int i = 0; i < 4; ++i)
        qf[i] = (g == 0)
              ? frag_lo(qpack + (size_t)(b * HW + nb + 16 * i + ln) * 8)
              : zf.v;
#endif

    f32x4 o[4][4];
    float psum[4];
#pragma unroll
    for (int i = 0; i < 4; ++i) {
#pragma unroll
        for (int j = 0; j < 4; ++j) o[i][j] = (f32x4){0,0,0,0};
        psum[i] = 0.f;
    }

    const int mq = w * 512;                // this wave's m-slice
    const unsigned short* kb = kpack + (size_t)(b * HW + mq + ln) * 8;
    const unsigned short* vwin = vt3 + ((size_t)b * 128 + w * 16) * 2048
                               + ln * 32 + 8 * g;

#pragma unroll 2
    for (int ch = 0; ch < 16; ++ch) {
        const unsigned short* kp = kb + ch * 256;    // 32 K-rows x 8 ushorts
#if HAVE_K16
        s16x4 kf0 = (g < 2) ? frag4s(kp + 4 * g)       : z4;
        s16x4 kf1 = (g < 2) ? frag4s(kp + 128 + 4 * g) : z4;
#else
        bf16x8 kf0 = (g == 0) ? frag_lo(kp)       : zf.v;
        bf16x8 kf1 = (g == 0) ? frag_lo(kp + 128) : zf.v;
#endif
        const unsigned short* vp = vwin + (size_t)ch * 2048;
        bf16x8 vf0 = *(const bf16x8*)(vp);           // c rows ln
        bf16x8 vf1 = *(const bf16x8*)(vp + 512);     // c rows 16+ln
        bf16x8 vf2 = *(const bf16x8*)(vp + 1024);    // c rows 32+ln
        bf16x8 vf3 = *(const bf16x8*)(vp + 1536);    // c rows 48+ln

        const f32x4 z = {0.f, 0.f, 0.f, 0.f};
#pragma unroll
        for (int i = 0; i < 4; ++i) {
#if HAVE_K16
            f32x4 s0 = SMFMA16x16(kf0, qf[i], z);
            f32x4 s1 = SMFMA16x16(kf1, qf[i], z);
#else
            f32x4 s0 = MFMA16(kf0, qf[i], z);
            f32x4 s1 = MFMA16(kf1, qf[i], z);
#endif
            F8 pa;
            float sacc = 0.f;
#pragma unroll
            for (int r = 0; r < 4; ++r) {
                float e0 = EXP2(s0[r]);
                float e1 = EXP2(s1[r]);
                sacc += e0 + e1;
                pa.h[r]     = (__bf16)e0;
                pa.h[r + 4] = (__bf16)e1;
            }
            psum[i] += sacc;
            o[i][0] = MFMA16(pa.v, vf0, o[i][0]);
            o[i][1] = MFMA16(pa.v, vf1, o[i][1]);
            o[i][2] = MFMA16(pa.v, vf2, o[i][2]);
            o[i][3] = MFMA16(pa.v, vf3, o[i][3]);
        }
    }

    // deferred cross-lane L reduce (sum lane bits 4,5)
#pragma unroll
    for (int i = 0; i < 4; ++i) {
        psum[i] += __shfl_xor(psum[i], 16);
        psum[i] += __shfl_xor(psum[i], 32);
    }

    // two-phase slab merge
    if (w < 4) {
#pragma unroll
        for (int i = 0; i < 4; ++i)
#pragma unroll
            for (int r = 0; r < 4; ++r)
#pragma unroll
                for (int j = 0; j < 4; ++j)
                    ldsO[w][16 * i + 4 * g + r][16 * j + ln] = f2bf(o[i][j][r]);
    }
    if (lane < 16) {
#pragma unroll
        for (int i = 0; i < 4; ++i)
            ldsL[w][16 * i + ln] = psum[i];
    }
    __syncthreads();
    if (w >= 4) {
        const int s = w - 4;
#pragma unroll
        for (int i = 0; i < 4; ++i)
#pragma unroll
            for (int r = 0; r < 4; ++r)
#pragma unroll
                for (int j = 0; j < 4; ++j) {
                    unsigned short* p = &ldsO[s][16 * i + 4 * g + r][16 * j + ln];
                    *p = f2bf(bf2f(*p) + o[i][j][r]);
                }
    }
    __syncthreads();

    const int q  = tid & 63;               // query row 0..63
    const int cg = tid >> 6;               // 0..7
    float L = 0.f;
#pragma unroll
    for (int wv = 0; wv < 8; ++wv) L += ldsL[wv][q];
    const float inv = 1.0f / L;
    const float gm  = gamma[0];
#pragma unroll
    for (int jj = 0; jj < 8; ++jj) {
        const int c = cg + 8 * jj;         // 0..63
        float Ov = bf2f(ldsO[0][q][c]) + bf2f(ldsO[1][q][c])
                 + bf2f(ldsO[2][q][c]) + bf2f(ldsO[3][q][c]);
        const size_t idx = (size_t)(b * 64 + c) * HW + nb + q;
        out[idx] = fmaf(gm, Ov * inv, x[idx]);
    }
}

extern "C" void kernel_launch(void* const* d_in, const int* in_sizes, int n_in,
                              void* d_out, int out_size, void* d_ws, size_t ws_size,
                              hipStream_t stream) {
    const float* x  = (const float*)d_in[0];
    const float* Wq = (const float*)d_in[1];
    const float* bq = (const float*)d_in[2];
    const float* Wk = (const float*)d_in[3];
    const float* bk = (const float*)d_in[4];
    const float* Wv = (const float*)d_in[5];
    const float* bv = (const float*)d_in[6];
    const float* gm = (const float*)d_in[7];

    // ws layout: qpack 256KB | kpack 256KB | vt3 2MB  (total 2.5MB)
    unsigned short* qpack = (unsigned short*)d_ws;
    unsigned short* kpack = qpack + 4 * HW * 8;
    unsigned short* vt3   = kpack + 4 * HW * 8;
    float* out = (float*)d_out;

    proj_kernel<<<1024, 256, 0, stream>>>(x, Wq, bq, Wk, bk, Wv, bv,
                                          qpack, kpack, vt3);
    attn_kernel<<<256, 512, 0, stream>>>(qpack, kpack, vt3, x, gm, out);
}